// Round 7
// baseline (418.082 us; speedup 1.0000x reference)
//
#include <hip/hip_runtime.h>

#define NN 50000
#define NE 800000
#define NEB 3125   // NE/256 edge blocks (1 edge/thread; 3125*256 == NE exactly)
#define NHB 3125   // NN/16 projection blocks / node tiles
#define NTILES 3125
#define NKEY (8 * NN)   // (group, node) CSR keys
// inputs: node_features[NN*64] f32, edge_features[NE*32] f32, src[NE] i32,
//         dst[NE] i32, w_group[160] f32, w_srcattn[96] f32, w_lin[160*64] f32
// out: [NN*64] f32
//
// Algebra: a = ef·wg[0:32] + p1[src] + p2[dst]; t = p3[src]; u = ef·wa[64:96]
//          gamma = e^a / den_src[src]; s = t + gamma*u
//
// XCD-partitioned CSR, conservative variant: segments keyed (g,dst) with
// g = blockIdx&7 -- the SAME formula in the histogram pass and k_edge, so the
// keying is consistent regardless of how blocks map to XCDs; under
// round-robin dispatch same-g blocks share an XCD, so recA lines get a single
// writer XCD whose L2 merges the 16B records into full-line writebacks
// (r4 evidence: unpartitioned scatter wrote exactly one dirty 64B line per
// 16B record, 51MB + ~51MB allocate-fill).
// Machinery is r4's proven path: byte-packed histogram WITH atomic-return
// (rank = extracted byte of returned word; 4 keys/word, per-(g,n) count ~2
// Poisson << 255), order-arbitrary chunked scan -> offG, and pure-load
// pos = offG[key]+rank in k_edge (no cursor atomics). pos clamped to NE-1 so
// any logic error fails absmax instead of faulting.
// k_reduce walks node n's 8 runs via a branchless select chain.
// hb[n][160] bf16 row = [bf16(h) | accum] is the GEMM A-matrix; wlbT is the
// pre-transposed bf16 w_lin for 16B B-fragment loads.

typedef __attribute__((ext_vector_type(8))) short bf16x8;  // 8 bf16 (4 VGPRs)
typedef __attribute__((ext_vector_type(4))) short s16x4;
typedef __attribute__((ext_vector_type(4))) float f32x4;
typedef __attribute__((ext_vector_type(4))) int   i32x4;

static __device__ __forceinline__ short f2bf(float f) {
    unsigned int u = __float_as_uint(f);
    u += 0x7FFFu + ((u >> 16) & 1u);       // round-to-nearest-even
    return (short)(u >> 16);
}
static __device__ __forceinline__ float bf2f(short b) {
    return __uint_as_float(((unsigned)(unsigned short)b) << 16);
}

// ---------------------------------------------------------------------------
// Pass 0 (fused): blocks [0,NEB): byte-packed (g,dst) histogram WITH return;
// rank[e] = old count of key (g,dst[e]) = extracted byte. Only consumer of
// the return is a coalesced 4B store -> latency hidden (r0/r4-proven shape).
// blocks [NEB,NEB+NHB): per-node projections (16 lanes/node, shfl reduce)
//   p1 = h·wg[32:96] ; pd = h·wg[96:160] ; dp[n].y = h·wa[0:64] (p3)
// plus bf16 copy of the h row into hb[n][0:64] (GEMM A + k_reduce gather).
// ---------------------------------------------------------------------------
__global__ __launch_bounds__(256) void k_pre(
    const float* __restrict__ h, const int* __restrict__ dst,
    const float* __restrict__ wg, const float* __restrict__ wa,
    unsigned* __restrict__ cntP, int* __restrict__ rank,
    float* __restrict__ p1, float* __restrict__ pd, float* __restrict__ dpf,
    short* __restrict__ hb)
{
    int tid = threadIdx.x;
    if (blockIdx.x < NEB) {
        int e = blockIdx.x * 256 + tid;            // always < NE (exact cover)
        int g = blockIdx.x & 7;
        int key = g * NN + dst[e];
        int sh = (key & 3) * 8;
        unsigned old = atomicAdd(&cntP[key >> 2], 1u << sh);
        rank[e] = (int)((old >> sh) & 255u);
        return;
    }
    __shared__ float4 ls[16], ld[16], lt[16];
    if (tid < 16)      ls[tid]      = ((const float4*)wg)[8 + tid];   // wg[32:96)
    else if (tid < 32) ld[tid - 16] = ((const float4*)wg)[8 + tid];   // wg[96:160)
    else if (tid < 48) lt[tid - 32] = ((const float4*)wa)[tid - 32];  // wa[0:64)
    __syncthreads();
    int n = (blockIdx.x - NEB) * 16 + (tid >> 4);
    if (n >= NN) return;
    int l16 = tid & 15;
    float4 v = ((const float4*)(h + (size_t)n * 64))[l16];
    s16x4 hv;
    hv[0] = f2bf(v.x); hv[1] = f2bf(v.y); hv[2] = f2bf(v.z); hv[3] = f2bf(v.w);
    *(s16x4*)(hb + (size_t)n * 160 + l16 * 4) = hv;
    float4 w1 = ls[l16], w2 = ld[l16], w3 = lt[l16];
    float s1 = v.x*w1.x + v.y*w1.y + v.z*w1.z + v.w*w1.w;
    float s2 = v.x*w2.x + v.y*w2.y + v.z*w2.z + v.w*w2.w;
    float s3 = v.x*w3.x + v.y*w3.y + v.z*w3.z + v.w*w3.w;
    #pragma unroll
    for (int m = 8; m; m >>= 1) {
        s1 += __shfl_xor(s1, m);
        s2 += __shfl_xor(s2, m);
        s3 += __shfl_xor(s3, m);
    }
    if (l16 == 0) { p1[n] = s1; pd[n] = s2; dpf[2 * n + 1] = s3; }
}

// ---------------------------------------------------------------------------
// Pass 1: blocks [0,1563): order-arbitrary wave-chunked prefix over the 400k
// byte-packed (g,n) counters -> offG (stable run bases; a 64-key chunk is
// contiguous, so each (g,n) run occupies [offG[key], offG[key]+cnt[key])
// and all runs partition [0,NE)).
// blocks [1563,1603): one-time w_lin -> wlbT bf16 transpose.
// ---------------------------------------------------------------------------
__global__ __launch_bounds__(256) void k_assign(
    const unsigned* __restrict__ cntP, int* __restrict__ offG,
    int* __restrict__ gtotal, const float* __restrict__ wl,
    short* __restrict__ wlbT)
{
    if (blockIdx.x >= 1563) {
        int idx = (blockIdx.x - 1563) * 256 + threadIdx.x;   // [0,10240)
        int k = idx >> 6, nn = idx & 63;
        wlbT[nn * 160 + k] = f2bf(wl[idx]);
        return;
    }
    int k = blockIdx.x * 256 + threadIdx.x;    // key in [0, 400128)
    int lane = threadIdx.x & 63;
    int c = 0;
    if (k < NKEY) c = (int)((cntP[k >> 2] >> ((k & 3) * 8)) & 255u);
    int pre = c;
    #pragma unroll
    for (int d = 1; d < 64; d <<= 1) {
        int v = __shfl_up(pre, d);
        if (lane >= d) pre += v;
    }
    int base = 0;
    if (lane == 63) base = atomicAdd(gtotal, pre);
    base = __shfl(base, 63);
    if (k < NKEY) offG[k] = base + pre - c;
}

// ---------------------------------------------------------------------------
// Pass 2: edge scoring, 1 edge/thread, PURE-LOAD slot address
// pos = offG[g*NN+d] + rank[e] (no atomic dependency; r4-proven shape).
// pos clamped (free guard: logic error -> wrong answer, not a fault).
// recA region lines are single-g -> single-XCD -> L2-merged writebacks.
// den atomic fire-and-forget.
// ---------------------------------------------------------------------------
__global__ __launch_bounds__(256) void k_edge(
    const float* __restrict__ ef, const int* __restrict__ src,
    const int* __restrict__ dst, const int* __restrict__ rank,
    const float* __restrict__ wg, const float* __restrict__ wa,
    const float* __restrict__ p1, const float* __restrict__ pd,
    float* __restrict__ dpf, const int* __restrict__ offG,
    i32x4* __restrict__ recA)
{
    __shared__ float4 lwe[8], lae[8];
    int tid = threadIdx.x;
    if (tid < 8)       lwe[tid]     = ((const float4*)wg)[tid];          // wg[0:32)
    else if (tid < 16) lae[tid - 8] = ((const float4*)wa)[tid - 8 + 16]; // wa[64:96)
    __syncthreads();
    int e = blockIdx.x * 256 + tid;            // always < NE (exact cover)
    int g = blockIdx.x & 7;
    int s = src[e], d = dst[e], rk = rank[e];
    float p1v = p1[s], pdv = pd[d];
    int pos = offG[g * NN + d] + rk;
    pos = (pos < NE) ? pos : (NE - 1);         // structural OOB guard
    const float4* e4 = (const float4*)(ef + (size_t)e * 32);
    float a = 0.f, u = 0.f;
    #pragma unroll
    for (int q = 0; q < 8; ++q) {
        float4 v = e4[q], w = lwe[q], w2 = lae[q];
        a += v.x*w.x  + v.y*w.y  + v.z*w.z  + v.w*w.w;
        u += v.x*w2.x + v.y*w2.y + v.z*w2.z + v.w*w2.w;
    }
    float ev = __expf(a + p1v + pdv);
    atomicAdd(&dpf[2 * s], ev);            // den_src; no return needed
    recA[pos] = (i32x4){s, e, __float_as_int(ev), __float_as_int(u)};
}

// ---------------------------------------------------------------------------
// Pass 3: wave-per-node segmented softmax-reduce, 8-wide main loop.
// Node n's records live in 8 runs (one per group g): [offG[g*NN+n],
// offG[g*NN+n] + cnt[g*NN+n]). Global record q -> address via a branchless
// 7-select chain (adj[g] = off_g - Pv[g]); run ranges are in-bounds by
// construction of the scan. Record order within a segment is arbitrary
// (fp sum reorder only). Gathers/math identical to r4: h rows as bf16 from
// hb[src][0:64]; ef rows split across lane halves; rcp; bf16 accum store
// into hb[n][64:160].
// ---------------------------------------------------------------------------
__global__ __launch_bounds__(256) void k_reduce(
    const float* __restrict__ ef, const unsigned* __restrict__ cntP,
    const int* __restrict__ offG, const float2* __restrict__ dp,
    const i32x4* __restrict__ recA, short* __restrict__ hb)
{
    int n = blockIdx.x * 4 + (threadIdx.x >> 6);
    if (n >= NN) return;
    int lane = threadIdx.x & 63;
    bool up = lane >= 32;
    int l5 = lane & 31;

    int Pv[9]; int adj[8];
    Pv[0] = 0;
    #pragma unroll
    for (int g = 0; g < 8; ++g) {
        int key = g * NN + n;
        int o = offG[key];
        int c = (int)((cntP[key >> 2] >> ((key & 3) * 8)) & 255u);
        Pv[g + 1] = Pv[g] + c;
        adj[g] = o - Pv[g];
    }
    int deg = Pv[8];

    float acch = 0.f, acce = 0.f, den = 0.f;
    int j = 0;
    for (; j + 8 <= deg; j += 8) {
        i32x4 r[8];
        #pragma unroll
        for (int t = 0; t < 8; ++t) {
            int q = j + t;
            int aq = adj[0];
            #pragma unroll
            for (int g = 1; g < 8; ++g) aq = (q >= Pv[g]) ? adj[g] : aq;
            r[t] = recA[aq + q];
        }
        float2 dv[8]; float hv[8];
        #pragma unroll
        for (int t = 0; t < 8; ++t) {
            dv[t] = dp[r[t][0]];
            hv[t] = bf2f(hb[(size_t)(unsigned)r[t][0] * 160 + lane]);
        }
        float efv[4];
        #pragma unroll
        for (int t = 0; t < 4; ++t) {
            int ee = up ? r[2*t+1][1] : r[2*t][1];
            efv[t] = ef[((unsigned)ee << 5) + l5];
        }
        float g[8], s[8];
        #pragma unroll
        for (int t = 0; t < 8; ++t) {
            g[t] = __int_as_float(r[t][2]) * __builtin_amdgcn_rcpf(dv[t].x);
            s[t] = __expf(dv[t].y + g[t] * __int_as_float(r[t][3]));
            den  += s[t];
            acch += s[t] * hv[t];
        }
        #pragma unroll
        for (int t = 0; t < 4; ++t) {
            float w = up ? s[2*t+1]*g[2*t+1] : s[2*t]*g[2*t];
            acce += w * efv[t];
        }
    }
    if (j + 4 <= deg) {
        i32x4 r[4];
        #pragma unroll
        for (int t = 0; t < 4; ++t) {
            int q = j + t;
            int aq = adj[0];
            #pragma unroll
            for (int g = 1; g < 8; ++g) aq = (q >= Pv[g]) ? adj[g] : aq;
            r[t] = recA[aq + q];
        }
        float2 dv[4]; float hv[4];
        #pragma unroll
        for (int t = 0; t < 4; ++t) {
            dv[t] = dp[r[t][0]];
            hv[t] = bf2f(hb[(size_t)(unsigned)r[t][0] * 160 + lane]);
        }
        float efv[2];
        #pragma unroll
        for (int t = 0; t < 2; ++t) {
            int ee = up ? r[2*t+1][1] : r[2*t][1];
            efv[t] = ef[((unsigned)ee << 5) + l5];
        }
        float g[4], s[4];
        #pragma unroll
        for (int t = 0; t < 4; ++t) {
            g[t] = __int_as_float(r[t][2]) * __builtin_amdgcn_rcpf(dv[t].x);
            s[t] = __expf(dv[t].y + g[t] * __int_as_float(r[t][3]));
            den  += s[t];
            acch += s[t] * hv[t];
        }
        #pragma unroll
        for (int t = 0; t < 2; ++t) {
            float w = up ? s[2*t+1]*g[2*t+1] : s[2*t]*g[2*t];
            acce += w * efv[t];
        }
        j += 4;
    }
    for (; j < deg; ++j) {
        int q = j;
        int aq = adj[0];
        #pragma unroll
        for (int g = 1; g < 8; ++g) aq = (q >= Pv[g]) ? adj[g] : aq;
        i32x4 r = recA[aq + q];
        float2 dt = dp[r[0]];
        float gg = __int_as_float(r[2]) * __builtin_amdgcn_rcpf(dt.x);
        float sx = __expf(dt.y + gg * __int_as_float(r[3]));
        den += sx;
        acch += sx * bf2f(hb[(size_t)(unsigned)r[0] * 160 + lane]);
        if (!up) acce += sx * gg * ef[((unsigned)r[1] << 5) + l5];
    }
    acce += __shfl_xor(acce, 32);          // fold odd-record (upper-lane) part
    float inv = (deg > 0) ? __builtin_amdgcn_rcpf(den) : 0.f;
    size_t hbase = (size_t)n * 160;
    hb[hbase + 64 + lane] = f2bf(acch * inv);
    if (!up) hb[hbase + 128 + l5] = f2bf(acce * inv);
}

// ---------------------------------------------------------------------------
// Pass 4: out = relu(hb @ w_lin) as an MFMA bf16 GEMM. A rows are bf16 in
// hb[n][160]; B-frags are 16B vector loads from wlbT[64][160]. Grid 391
// blocks (2 tiles/wave). Layouts (m89/m120-verified): A[m=lane&15][k=quad*8+j],
// B[k=quad*8+j][n=lane&15], D[row=quad*4+reg][col=lane&15].
// ---------------------------------------------------------------------------
__global__ __launch_bounds__(256) void k_node_update(
    const short* __restrict__ hb, const short* __restrict__ wlbT,
    float* __restrict__ out)
{
    int lane = threadIdx.x & 63;
    int col  = lane & 15;
    int quad = lane >> 4;
    int wid  = blockIdx.x * 4 + (threadIdx.x >> 6);
    int nwaves = gridDim.x * 4;

    bf16x8 bfr[5][4];
    #pragma unroll
    for (int nt = 0; nt < 4; ++nt) {
        const short* bp = wlbT + (size_t)(nt * 16 + col) * 160 + quad * 8;
        #pragma unroll
        for (int kc = 0; kc < 5; ++kc)
            bfr[kc][nt] = *(const bf16x8*)(bp + kc * 32);
    }

    for (int tile = wid; tile < NTILES; tile += nwaves) {
        int n = tile * 16 + col;             // A-operand node (m = lane&15)
        f32x4 acc[4];
        #pragma unroll
        for (int nt = 0; nt < 4; ++nt) acc[nt] = (f32x4){0.f, 0.f, 0.f, 0.f};

        const short* hrow = hb + (size_t)n * 160 + quad * 8;
        #pragma unroll
        for (int kc = 0; kc < 5; ++kc) {
            bf16x8 af = *(const bf16x8*)(hrow + kc * 32);
            #pragma unroll
            for (int nt = 0; nt < 4; ++nt)
                acc[nt] = __builtin_amdgcn_mfma_f32_16x16x32_bf16(
                    af, bfr[kc][nt], acc[nt], 0, 0, 0);
        }

        // D: row = quad*4 + r (node within tile), col = nt*16 + (lane&15)
        #pragma unroll
        for (int nt = 0; nt < 4; ++nt) {
            #pragma unroll
            for (int r = 0; r < 4; ++r) {
                int node = tile * 16 + quad * 4 + r;
                out[(size_t)node * 64 + nt * 16 + col] = fmaxf(acc[nt][r], 0.f);
            }
        }
    }
}

// ---------------------------------------------------------------------------
// Workspace layout (4-byte words):
//   [0, 2NN)               dp     (float2 {den_src, p3}; zeroed)
//   [2NN, 4NN)             cntP   (byte-packed (g,n) counters; zeroed)
//   [4NN, 4NN+16)          gtotal (int, zeroed)
//   [4NN+16, 12NN+16)      offG   (int[8NN]; stable run bases)
//   [12NN+16, 13NN+16)     p1     (float)
//   [13NN+16, 14NN+16)     pd     (float)
//   [14NN+16, +NE)         rank   (int[NE])
//   [+NE, +NE+5120)        wlbT   (bf16 [64][160])
//   [.., +4NE)             recA   (i32x4; byte off 6020544 %16==0)
//   [.., +80NN)            hb     (bf16 [NN][160]; byte off 18820544 %16==0)
// total = 14NN+16 + 5NE + 5120 + 80NN = 8,705,136 words ≈ 34.8 MB
// ---------------------------------------------------------------------------
extern "C" void kernel_launch(void* const* d_in, const int* in_sizes, int n_in,
                              void* d_out, int out_size, void* d_ws, size_t ws_size,
                              hipStream_t stream)
{
    const float* h   = (const float*)d_in[0];
    const float* ef  = (const float*)d_in[1];
    const int*   src = (const int*)d_in[2];
    const int*   dst = (const int*)d_in[3];
    const float* wg  = (const float*)d_in[4];
    const float* wa  = (const float*)d_in[5];
    const float* wl  = (const float*)d_in[6];
    float* out = (float*)d_out;

    float*    ws     = (float*)d_ws;
    float*    dpf    = ws;                       // float2 view at same addr
    unsigned* cntP   = (unsigned*)(ws + 2 * NN);
    int*      gtotal = (int*)(ws + 4 * NN);
    int*      offG   = (int*)(ws + 4 * NN + 16);
    float*    p1     = ws + 12 * NN + 16;
    float*    pd     = ws + 13 * NN + 16;
    int*      rank   = (int*)(ws + 14 * NN + 16);
    short*    wlbT   = (short*)(ws + 14 * NN + 16 + NE);
    i32x4*    recA   = (i32x4*)(ws + 14 * NN + 16 + NE + 5120);
    short*    hb     = (short*)(ws + 14 * NN + 16 + 5 * NE + 5120);

    hipMemsetAsync(d_ws, 0, (size_t)(4 * NN + 16) * sizeof(float), stream);

    k_pre<<<NEB + NHB, 256, 0, stream>>>(h, dst, wg, wa, cntP, rank, p1, pd,
                                         dpf, hb);
    k_assign<<<1603, 256, 0, stream>>>(cntP, offG, gtotal, wl, wlbT);
    k_edge<<<NEB, 256, 0, stream>>>(ef, src, dst, rank, wg, wa, p1, pd, dpf,
                                    offG, recA);
    k_reduce<<<(NN + 3) / 4, 256, 0, stream>>>(ef, cntP, offG,
                                               (const float2*)dpf, recA, hb);
    k_node_update<<<391, 256, 0, stream>>>(hb, wlbT, out);
}

// Round 8
// 343.185 us; speedup vs baseline: 1.2182x; 1.2182x over previous
//
#include <hip/hip_runtime.h>

#define NN 50000
#define NE 800000
#define NEB 3125   // NE/256 edge blocks (1 edge/thread; 3125*256 == NE exactly)
#define NHB 3125   // NN/16 projection blocks / node tiles
#define NTILES 3125
// inputs: node_features[NN*64] f32, edge_features[NE*32] f32, src[NE] i32,
//         dst[NE] i32, w_group[160] f32, w_srcattn[96] f32, w_lin[160*64] f32
// out: [NN*64] f32
//
// Algebra: a = ef·wg[0:32] + p1[src] + p2[dst]; t = p3[src]; u = ef·wa[64:96]
//          gamma = e^a / den_src[src]; s = t + gamma*u
//
// Structure = r4 (best-passing, 339.9us) with ONE change: den_src atomics go
// to 8 partial banks dpf8[g][n], g = blockIdx&7, folded by k_den before
// k_reduce. Rationale: k_edge is serialization-bound (VALU 3%, HBM 17%);
// 800k atomicAdds into a 400KB region = ~128 colliding RMWs per 64B line,
// ping-ponging across all 8 XCDs. Banking cuts per-line collisions 8x
// (mapping-independent) and makes lines single-XCD under round-robin.
// r7 lesson: g-major partitioned CSR regressed k_reduce (+16us VALU select
// chain, +20MB fetch from 8-way record splits) -> records stay node-
// contiguous here; only the denominator is banked.
// CSR: hist with rank (atomic-return hidden in k_pre) -> off prefix ->
// k_edge scatters the FULL 16B record {src,e,e^a,u} at off[d]+rank[e].
// k_reduce gathers h rows as bf16 from hb; hb[n][160] = [bf16(h) | accum]
// is the GEMM A-matrix; wlbT = pre-transposed bf16 w_lin (16B B-frag loads).

typedef __attribute__((ext_vector_type(8))) short bf16x8;  // 8 bf16 (4 VGPRs)
typedef __attribute__((ext_vector_type(4))) short s16x4;
typedef __attribute__((ext_vector_type(4))) float f32x4;
typedef __attribute__((ext_vector_type(4))) int   i32x4;

static __device__ __forceinline__ short f2bf(float f) {
    unsigned int u = __float_as_uint(f);
    u += 0x7FFFu + ((u >> 16) & 1u);       // round-to-nearest-even
    return (short)(u >> 16);
}
static __device__ __forceinline__ float bf2f(short b) {
    return __uint_as_float(((unsigned)(unsigned short)b) << 16);
}

// ---------------------------------------------------------------------------
// Pass 0 (fused): blocks [0,NEB): dst histogram + per-edge rank (the atomic
// return's only consumer is a coalesced 4B store -> latency hidden).
// blocks [NEB,NEB+NHB): per-node projections (16 lanes/node, shfl reduce)
//   p1 = h·wg[32:96] ; pd = h·wg[96:160] ; dp[n].y = h·wa[0:64] (p3)
// plus bf16 copy of the h row into hb[n][0:64] (GEMM A + k_reduce gather).
// ---------------------------------------------------------------------------
__global__ __launch_bounds__(256) void k_pre(
    const float* __restrict__ h, const int* __restrict__ dst,
    const float* __restrict__ wg, const float* __restrict__ wa,
    int* __restrict__ cnt, int* __restrict__ rank,
    float* __restrict__ p1, float* __restrict__ pd, float* __restrict__ dpf,
    short* __restrict__ hb)
{
    int tid = threadIdx.x;
    if (blockIdx.x < NEB) {
        int e = blockIdx.x * 256 + tid;            // always < NE (exact cover)
        rank[e] = atomicAdd(&cnt[dst[e]], 1);
        return;
    }
    __shared__ float4 ls[16], ld[16], lt[16];
    if (tid < 16)      ls[tid]      = ((const float4*)wg)[8 + tid];   // wg[32:96)
    else if (tid < 32) ld[tid - 16] = ((const float4*)wg)[8 + tid];   // wg[96:160)
    else if (tid < 48) lt[tid - 32] = ((const float4*)wa)[tid - 32];  // wa[0:64)
    __syncthreads();
    int n = (blockIdx.x - NEB) * 16 + (tid >> 4);
    if (n >= NN) return;
    int l16 = tid & 15;
    float4 v = ((const float4*)(h + (size_t)n * 64))[l16];
    s16x4 hv;
    hv[0] = f2bf(v.x); hv[1] = f2bf(v.y); hv[2] = f2bf(v.z); hv[3] = f2bf(v.w);
    *(s16x4*)(hb + (size_t)n * 160 + l16 * 4) = hv;
    float4 w1 = ls[l16], w2 = ld[l16], w3 = lt[l16];
    float s1 = v.x*w1.x + v.y*w1.y + v.z*w1.z + v.w*w1.w;
    float s2 = v.x*w2.x + v.y*w2.y + v.z*w2.z + v.w*w2.w;
    float s3 = v.x*w3.x + v.y*w3.y + v.z*w3.z + v.w*w3.w;
    #pragma unroll
    for (int m = 8; m; m >>= 1) {
        s1 += __shfl_xor(s1, m);
        s2 += __shfl_xor(s2, m);
        s3 += __shfl_xor(s3, m);
    }
    if (l16 == 0) { p1[n] = s1; pd[n] = s2; dpf[2 * n + 1] = s3; }
}

// ---------------------------------------------------------------------------
// Pass 1: blocks [0,196): contiguous (order-arbitrary) segment bases from cnt.
// blocks [196,236): one-time w_lin -> wlbT bf16 transpose.
// ---------------------------------------------------------------------------
__global__ __launch_bounds__(256) void k_assign(
    const int* __restrict__ cnt, int* __restrict__ off, int* __restrict__ gtotal,
    const float* __restrict__ wl, short* __restrict__ wlbT)
{
    if (blockIdx.x >= 196) {
        int idx = (blockIdx.x - 196) * 256 + threadIdx.x;   // [0,10240)
        int k = idx >> 6, nn = idx & 63;
        wlbT[nn * 160 + k] = f2bf(wl[idx]);
        return;
    }
    int n = blockIdx.x * 256 + threadIdx.x;
    int lane = threadIdx.x & 63;
    int c = (n < NN) ? cnt[n] : 0;
    int pre = c;
    #pragma unroll
    for (int d = 1; d < 64; d <<= 1) {
        int v = __shfl_up(pre, d);
        if (lane >= d) pre += v;
    }
    int base = 0;
    if (lane == 63) base = atomicAdd(gtotal, pre);
    base = __shfl(base, 63);
    if (n < NN) off[n] = base + pre - c;
}

// ---------------------------------------------------------------------------
// Pass 2: edge scoring, 1 edge/thread. pos = off[d]+rank[e] (pure loads, no
// atomic dependency). Full 16B record scatter. den_src atomic goes to the
// blockIdx&7 bank of dpf8 -- fire-and-forget, 8x fewer collisions per line.
// ---------------------------------------------------------------------------
__global__ __launch_bounds__(256) void k_edge(
    const float* __restrict__ ef, const int* __restrict__ src,
    const int* __restrict__ dst, const int* __restrict__ rank,
    const float* __restrict__ wg, const float* __restrict__ wa,
    const float* __restrict__ p1, const float* __restrict__ pd,
    float* __restrict__ dpf8, const int* __restrict__ off,
    i32x4* __restrict__ recA)
{
    __shared__ float4 lwe[8], lae[8];
    int tid = threadIdx.x;
    if (tid < 8)       lwe[tid]     = ((const float4*)wg)[tid];          // wg[0:32)
    else if (tid < 16) lae[tid - 8] = ((const float4*)wa)[tid - 8 + 16]; // wa[64:96)
    __syncthreads();
    int e = blockIdx.x * 256 + tid;            // always < NE (exact cover)
    int g = blockIdx.x & 7;
    int s = src[e], d = dst[e], rk = rank[e];
    float p1v = p1[s], pdv = pd[d];
    int pos = off[d] + rk;
    const float4* e4 = (const float4*)(ef + (size_t)e * 32);
    float a = 0.f, u = 0.f;
    #pragma unroll
    for (int q = 0; q < 8; ++q) {
        float4 v = e4[q], w = lwe[q], w2 = lae[q];
        a += v.x*w.x  + v.y*w.y  + v.z*w.z  + v.w*w.w;
        u += v.x*w2.x + v.y*w2.y + v.z*w2.z + v.w*w2.w;
    }
    float ev = __expf(a + p1v + pdv);
    atomicAdd(&dpf8[g * NN + s], ev);      // banked den_src; no return needed
    recA[pos] = (i32x4){s, e, __float_as_int(ev), __float_as_int(u)};
}

// ---------------------------------------------------------------------------
// Pass 2b: fold the 8 denominator banks into dp[n].x. 196 blocks, ~4us.
// Pure FP-reassociation of an already order-nondeterministic atomic sum.
// ---------------------------------------------------------------------------
__global__ __launch_bounds__(256) void k_den(
    const float* __restrict__ dpf8, float* __restrict__ dpf)
{
    int n = blockIdx.x * 256 + threadIdx.x;
    if (n >= NN) return;
    float s = 0.f;
    #pragma unroll
    for (int g = 0; g < 8; ++g) s += dpf8[g * NN + n];
    dpf[2 * n] = s;
}

// ---------------------------------------------------------------------------
// Pass 3: wave-per-node segmented softmax-reduce, 8-wide main loop (r4 form:
// node-contiguous recA stream, NO select chain -- r7 showed that costs
// +16us VALU + 20MB fetch). h rows gathered as BF16 from hb[src][0:64];
// ef rows split across lane halves; rcp; bf16 accum store into hb[n][64:160].
// ---------------------------------------------------------------------------
__global__ __launch_bounds__(256) void k_reduce(
    const float* __restrict__ ef, const int* __restrict__ cnt,
    const int* __restrict__ off, const float2* __restrict__ dp,
    const i32x4* __restrict__ recA, short* __restrict__ hb)
{
    int n = blockIdx.x * 4 + (threadIdx.x >> 6);
    if (n >= NN) return;
    int lane = threadIdx.x & 63;
    bool up = lane >= 32;
    int l5 = lane & 31;
    int deg = cnt[n], base = off[n];
    const i32x4* rp = recA + base;
    float acch = 0.f, acce = 0.f, den = 0.f;
    int j = 0;
    for (; j + 8 <= deg; j += 8) {
        i32x4 r[8];
        #pragma unroll
        for (int t = 0; t < 8; ++t) r[t] = rp[j + t];
        float2 dv[8]; float hv[8];
        #pragma unroll
        for (int t = 0; t < 8; ++t) {
            dv[t] = dp[r[t][0]];
            hv[t] = bf2f(hb[(size_t)(unsigned)r[t][0] * 160 + lane]);
        }
        float efv[4];
        #pragma unroll
        for (int t = 0; t < 4; ++t) {
            int ee = up ? r[2*t+1][1] : r[2*t][1];
            efv[t] = ef[((unsigned)ee << 5) + l5];
        }
        float g[8], s[8];
        #pragma unroll
        for (int t = 0; t < 8; ++t) {
            g[t] = __int_as_float(r[t][2]) * __builtin_amdgcn_rcpf(dv[t].x);
            s[t] = __expf(dv[t].y + g[t] * __int_as_float(r[t][3]));
            den  += s[t];
            acch += s[t] * hv[t];
        }
        #pragma unroll
        for (int t = 0; t < 4; ++t) {
            float w = up ? s[2*t+1]*g[2*t+1] : s[2*t]*g[2*t];
            acce += w * efv[t];
        }
    }
    if (j + 4 <= deg) {
        i32x4 r[4];
        #pragma unroll
        for (int t = 0; t < 4; ++t) r[t] = rp[j + t];
        float2 dv[4]; float hv[4];
        #pragma unroll
        for (int t = 0; t < 4; ++t) {
            dv[t] = dp[r[t][0]];
            hv[t] = bf2f(hb[(size_t)(unsigned)r[t][0] * 160 + lane]);
        }
        float efv[2];
        #pragma unroll
        for (int t = 0; t < 2; ++t) {
            int ee = up ? r[2*t+1][1] : r[2*t][1];
            efv[t] = ef[((unsigned)ee << 5) + l5];
        }
        float g[4], s[4];
        #pragma unroll
        for (int t = 0; t < 4; ++t) {
            g[t] = __int_as_float(r[t][2]) * __builtin_amdgcn_rcpf(dv[t].x);
            s[t] = __expf(dv[t].y + g[t] * __int_as_float(r[t][3]));
            den  += s[t];
            acch += s[t] * hv[t];
        }
        #pragma unroll
        for (int t = 0; t < 2; ++t) {
            float w = up ? s[2*t+1]*g[2*t+1] : s[2*t]*g[2*t];
            acce += w * efv[t];
        }
        j += 4;
    }
    for (; j < deg; ++j) {
        i32x4 r = rp[j];
        float2 dt = dp[r[0]];
        float g = __int_as_float(r[2]) * __builtin_amdgcn_rcpf(dt.x);
        float sx = __expf(dt.y + g * __int_as_float(r[3]));
        den += sx;
        acch += sx * bf2f(hb[(size_t)(unsigned)r[0] * 160 + lane]);
        if (!up) acce += sx * g * ef[((unsigned)r[1] << 5) + l5];
    }
    acce += __shfl_xor(acce, 32);          // fold odd-record (upper-lane) part
    float inv = (deg > 0) ? __builtin_amdgcn_rcpf(den) : 0.f;
    size_t hbase = (size_t)n * 160;
    hb[hbase + 64 + lane] = f2bf(acch * inv);
    if (!up) hb[hbase + 128 + l5] = f2bf(acce * inv);
}

// ---------------------------------------------------------------------------
// Pass 4: out = relu(hb @ w_lin) as an MFMA bf16 GEMM. A rows are bf16 in
// hb[n][160]; B-frags are 16B vector loads from wlbT[64][160]. Grid 391
// blocks (2 tiles/wave). Layouts (m89/m120-verified): A[m=lane&15][k=quad*8+j],
// B[k=quad*8+j][n=lane&15], D[row=quad*4+reg][col=lane&15].
// ---------------------------------------------------------------------------
__global__ __launch_bounds__(256) void k_node_update(
    const short* __restrict__ hb, const short* __restrict__ wlbT,
    float* __restrict__ out)
{
    int lane = threadIdx.x & 63;
    int col  = lane & 15;
    int quad = lane >> 4;
    int wid  = blockIdx.x * 4 + (threadIdx.x >> 6);
    int nwaves = gridDim.x * 4;

    bf16x8 bfr[5][4];
    #pragma unroll
    for (int nt = 0; nt < 4; ++nt) {
        const short* bp = wlbT + (size_t)(nt * 16 + col) * 160 + quad * 8;
        #pragma unroll
        for (int kc = 0; kc < 5; ++kc)
            bfr[kc][nt] = *(const bf16x8*)(bp + kc * 32);
    }

    for (int tile = wid; tile < NTILES; tile += nwaves) {
        int n = tile * 16 + col;             // A-operand node (m = lane&15)
        f32x4 acc[4];
        #pragma unroll
        for (int nt = 0; nt < 4; ++nt) acc[nt] = (f32x4){0.f, 0.f, 0.f, 0.f};

        const short* hrow = hb + (size_t)n * 160 + quad * 8;
        #pragma unroll
        for (int kc = 0; kc < 5; ++kc) {
            bf16x8 af = *(const bf16x8*)(hrow + kc * 32);
            #pragma unroll
            for (int nt = 0; nt < 4; ++nt)
                acc[nt] = __builtin_amdgcn_mfma_f32_16x16x32_bf16(
                    af, bfr[kc][nt], acc[nt], 0, 0, 0);
        }

        // D: row = quad*4 + r (node within tile), col = nt*16 + (lane&15)
        #pragma unroll
        for (int nt = 0; nt < 4; ++nt) {
            #pragma unroll
            for (int r = 0; r < 4; ++r) {
                int node = tile * 16 + quad * 4 + r;
                out[(size_t)node * 64 + nt * 16 + col] = fmaxf(acc[nt][r], 0.f);
            }
        }
    }
}

// ---------------------------------------------------------------------------
// Workspace layout (4-byte words):
//   [0, 8NN)               dpf8   (float[8][NN] banked den_src; zeroed)
//   [8NN, 9NN)             cnt    (int, zeroed)
//   [9NN, 9NN+16)          gtotal (int, zeroed)
//   [9NN+16, 11NN+16)      dp     (float2 {den_src, p3}; fully overwritten)
//   [11NN+16, 12NN+16)     off    (int)
//   [12NN+16, 13NN+16)     p1     (float)
//   [13NN+16, 14NN+16)     pd     (float)
//   [14NN+16, +NE)         rank   (int[NE])
//   [+NE, +NE+5120)        wlbT   (bf16 [64][160])
//   [.., +4NE)             recA   (i32x4; byte off 6020544 %16==0)
//   [.., +80NN)            hb     (bf16 [NN][160]; byte off 18820544 %16==0)
// total = 14NN+16 + 5NE + 5120 + 80NN = 8,705,136 words ≈ 34.8 MB (ran in r7)
// memset covers only [0, 9NN+16) = 1.8 MB.
// ---------------------------------------------------------------------------
extern "C" void kernel_launch(void* const* d_in, const int* in_sizes, int n_in,
                              void* d_out, int out_size, void* d_ws, size_t ws_size,
                              hipStream_t stream)
{
    const float* h   = (const float*)d_in[0];
    const float* ef  = (const float*)d_in[1];
    const int*   src = (const int*)d_in[2];
    const int*   dst = (const int*)d_in[3];
    const float* wg  = (const float*)d_in[4];
    const float* wa  = (const float*)d_in[5];
    const float* wl  = (const float*)d_in[6];
    float* out = (float*)d_out;

    float*  ws     = (float*)d_ws;
    float*  dpf8   = ws;
    int*    cnt    = (int*)(ws + 8 * NN);
    int*    gtotal = (int*)(ws + 9 * NN);
    float*  dpf    = ws + 9 * NN + 16;           // float2 view at same addr
    int*    off    = (int*)(ws + 11 * NN + 16);
    float*  p1     = ws + 12 * NN + 16;
    float*  pd     = ws + 13 * NN + 16;
    int*    rank   = (int*)(ws + 14 * NN + 16);
    short*  wlbT   = (short*)(ws + 14 * NN + 16 + NE);
    i32x4*  recA   = (i32x4*)(ws + 14 * NN + 16 + NE + 5120);
    short*  hb     = (short*)(ws + 14 * NN + 16 + 5 * NE + 5120);

    hipMemsetAsync(d_ws, 0, (size_t)(9 * NN + 16) * sizeof(float), stream);

    k_pre<<<NEB + NHB, 256, 0, stream>>>(h, dst, wg, wa, cnt, rank, p1, pd,
                                         dpf, hb);
    k_assign<<<236, 256, 0, stream>>>(cnt, off, gtotal, wl, wlbT);
    k_edge<<<NEB, 256, 0, stream>>>(ef, src, dst, rank, wg, wa, p1, pd, dpf8,
                                    off, recA);
    k_den<<<196, 256, 0, stream>>>(dpf8, dpf);
    k_reduce<<<(NN + 3) / 4, 256, 0, stream>>>(ef, cnt, off,
                                               (const float2*)dpf, recA, hb);
    k_node_update<<<391, 256, 0, stream>>>(hb, wlbT, out);
}